// Round 6
// baseline (299.461 us; speedup 1.0000x reference)
//
#include <hip/hip_runtime.h>

typedef unsigned short ushort_t;
typedef __attribute__((ext_vector_type(8))) __bf16 bf16x8;
typedef __attribute__((ext_vector_type(4))) float f32x4;

// B=32, N=128, INDIM=32, OUTDIM=64
// X: [32][128][128][32] f32; W: [32][64]; bias: [64]; n_nodes: [32] int
// X1t: [32][64][128][128] bf16  plane rows i, k=j contiguous
// X2t: [32][64][128][128] bf16  plane rows j, k=i contiguous
// out: [32][128][128][64] f32
// Masked rows (>= n_nodes[b]) are exact bf16 zeros in X1t/X2t -> k-truncation
// and tile zero-fill below are bit-identical to full compute.

__device__ __forceinline__ ushort_t f32_to_bf16(float v) {
    unsigned ui = __float_as_uint(v);
    ui += 0x7fffu + ((ui >> 16) & 1u);   // RNE (finite only)
    return (ushort_t)(ui >> 16);
}

union FragU { bf16x8 f; ushort_t u[8]; };
union Pack4 { ushort_t us[4]; uint2 v; };

// K1 (merged passes): Linear(32->64)+bias+ReLU+mask via mfma_16x16x32.
// Grid 2048: blocks 0..1023 pass A (r=i, t=j contiguous), 1024..2047 pass B
// (r=j, t=i strided; L1 pairs the half-line reads). Each block: 4 consecutive r.
__global__ __launch_bounds__(256) void lin_mfma_kernel(
        const float* __restrict__ X,
        const float* __restrict__ W1, const float* __restrict__ b1v,
        const float* __restrict__ W2, const float* __restrict__ b2v,
        const int* __restrict__ n_nodes,
        ushort_t* __restrict__ X1t, ushort_t* __restrict__ X2t) {
    __shared__ ushort_t sO[64 * 136];
    const int blk = blockIdx.x;
    const int pass = blk >> 10;
    const int idx = blk & 1023;
    const int b = idx >> 5, rg = idx & 31;           // r-group of 4
    const float* W    = pass ? W2  : W1;
    const float* bias = pass ? b2v : b1v;
    ushort_t* Out     = pass ? X2t : X1t;
    const int rstride = pass ? 32 : 4096;
    const int tstride = pass ? 4096 : 32;

    const int u = threadIdx.x;
    const int w = u >> 6, l = u & 63;
    const int quad = l >> 4, lid = l & 15;
    const int n = n_nodes[b];

    FragU bfrag[4];
    float bia[4];
    #pragma unroll
    for (int ni = 0; ni < 4; ++ni) {
        const int e = ni * 16 + lid;
        #pragma unroll
        for (int j = 0; j < 8; ++j)
            bfrag[ni].u[j] = f32_to_bf16(W[(quad * 8 + j) * 64 + e]);
        bia[ni] = bias[e];
    }

    for (int q = 0; q < 4; ++q) {
        const int r = rg * 4 + q;
        const bool rin = (r < n);
        if (rin) {
            const float* Xb = X + (size_t)b * 524288 + (size_t)r * rstride;
            #pragma unroll
            for (int s = 0; s < 2; ++s) {
                const int mt = w * 2 + s;           // wave w owns m-tiles 2w,2w+1
                const int t0b = mt * 16 + quad * 4;
                if (mt * 16 < n) {
                    const int m = mt * 16 + lid;
                    const float* xr = Xb + (size_t)m * tstride + quad * 8;
                    float4 x0 = *(const float4*)xr;
                    float4 x1 = *(const float4*)(xr + 4);
                    FragU af;
                    af.u[0] = f32_to_bf16(x0.x); af.u[1] = f32_to_bf16(x0.y);
                    af.u[2] = f32_to_bf16(x0.z); af.u[3] = f32_to_bf16(x0.w);
                    af.u[4] = f32_to_bf16(x1.x); af.u[5] = f32_to_bf16(x1.y);
                    af.u[6] = f32_to_bf16(x1.z); af.u[7] = f32_to_bf16(x1.w);
                    #pragma unroll
                    for (int ni = 0; ni < 4; ++ni) {
                        f32x4 acc = {};
                        acc = __builtin_amdgcn_mfma_f32_16x16x32_bf16(
                            af.f, bfrag[ni].f, acc, 0, 0, 0);
                        const int e = ni * 16 + lid;
                        Pack4 pk;
                        #pragma unroll
                        for (int rgi = 0; rgi < 4; ++rgi) {
                            const int t = t0b + rgi;
                            float v = (t < n) ? fmaxf(acc[rgi] + bia[ni], 0.f) : 0.f;
                            pk.us[rgi] = f32_to_bf16(v);
                        }
                        *(uint2*)(sO + e * 136 + t0b) = pk.v;
                    }
                } else {
                    Pack4 pk; pk.us[0] = pk.us[1] = pk.us[2] = pk.us[3] = 0;
                    #pragma unroll
                    for (int ni = 0; ni < 4; ++ni)
                        *(uint2*)(sO + (ni * 16 + lid) * 136 + t0b) = pk.v;
                }
            }
        }
        __syncthreads();
        {   // copy-out: 64 e-rows x 256 B; thread -> (e=u>>2, 64-B part=u&3)
            const int e = u >> 2, part = u & 3;
            ushort_t* gO = Out + ((size_t)(b * 64 + e) * 128 + r) * 128 + part * 32;
            if (rin) {
                const ushort_t* sRow = sO + e * 136 + part * 32;
                #pragma unroll
                for (int c = 0; c < 4; ++c)
                    *(uint4*)(gO + c * 8) = *(const uint4*)(sRow + c * 8);
            } else {
                uint4 z = {0, 0, 0, 0};
                #pragma unroll
                for (int c = 0; c < 4; ++c)
                    *(uint4*)(gO + c * 8) = z;
            }
        }
        __syncthreads();
    }
}

// K2' (fused matmul + transpose): block = (b, i-tile 16, j-tile 16).
// For each e (wave w owns e = w*16..w*16+15): C_e[16x16] = X1t rows i x X2t
// rows j over k (truncated at ceil(n/32)*32). C scatters into LDS [i][j][e]
// (j-stride 65 -> <=4-way on scatter), then out[b,i0:+16,j0:+16,:] written
// f32 fully coalesced. Masked tiles: pure zero-store, no reads, no LDS.
__global__ __launch_bounds__(256) void mmtr_kernel(
        const ushort_t* __restrict__ X1t, const ushort_t* __restrict__ X2t,
        float* __restrict__ out, const int* __restrict__ n_nodes) {
    __shared__ float sOut[16640];                // [i]*1040 + [j]*65 + [e]
    const int blk = blockIdx.x;                  // b*64 + it*8 + jt
    const int b = blk >> 6, it = (blk >> 3) & 7, jt = blk & 7;
    const int n = n_nodes[b];
    const int i0 = it * 16, j0 = jt * 16;
    const int u = threadIdx.x;
    float* ob = out + (size_t)b * 1048576 + (size_t)i0 * 8192 + (size_t)j0 * 64;

    if (i0 >= n || j0 >= n) {                    // block-uniform zero tile
        float4 z = {0.f, 0.f, 0.f, 0.f};
        #pragma unroll
        for (int itx = 0; itx < 16; ++itx) {
            int idx = itx * 256 + u;             // (i, j, e4) float4 id
            int i = idx >> 8, rem = idx & 255;
            int j = rem >> 4, e4 = (rem & 15) * 4;
            *(float4*)(ob + (size_t)i * 8192 + j * 64 + e4) = z;
        }
        return;
    }

    const int kmax = (n + 31) & ~31;
    const int w = u >> 6, l = u & 63;
    const int quad = l >> 4, lid = l & 15;
    const ushort_t* Ab = X1t + (size_t)b * 1048576 + (size_t)(i0 + lid) * 128;
    const ushort_t* Bb = X2t + (size_t)b * 1048576 + (size_t)(j0 + lid) * 128;

    for (int t = 0; t < 16; ++t) {
        const int e = w * 16 + t;
        const ushort_t* Ae = Ab + (size_t)e * 16384;
        const ushort_t* Be = Bb + (size_t)e * 16384;
        f32x4 acc = {};
        for (int k0 = 0; k0 < kmax; k0 += 32) {
            bf16x8 af = *(const bf16x8*)(Ae + k0 + quad * 8);
            bf16x8 bf = *(const bf16x8*)(Be + k0 + quad * 8);
            acc = __builtin_amdgcn_mfma_f32_16x16x32_bf16(af, bf, acc, 0, 0, 0);
        }
        // C/D: row i = quad*4+rg, col j = lid
        float* so = sOut + (quad * 4) * 1040 + lid * 65 + e;
        so[0]    = acc[0];
        so[1040] = acc[1];
        so[2080] = acc[2];
        so[3120] = acc[3];
    }
    __syncthreads();

    #pragma unroll
    for (int itx = 0; itx < 16; ++itx) {
        int idx = itx * 256 + u;                 // (i, j, e4) float4 id
        int i = idx >> 8, rem = idx & 255;
        int j = rem >> 4, e4 = (rem & 15) * 4;
        const float* sp = sOut + i * 1040 + j * 65 + e4;   // 4 contiguous -> b128
        float4 v;
        v.x = sp[0]; v.y = sp[1]; v.z = sp[2]; v.w = sp[3];
        *(float4*)(ob + (size_t)i * 8192 + j * 64 + e4) = v;
    }
}

extern "C" void kernel_launch(void* const* d_in, const int* in_sizes, int n_in,
                              void* d_out, int out_size, void* d_ws, size_t ws_size,
                              hipStream_t stream) {
    const float* X  = (const float*)d_in[0];
    const float* W1 = (const float*)d_in[1];
    const float* b1 = (const float*)d_in[2];
    const float* W2 = (const float*)d_in[3];
    const float* b2 = (const float*)d_in[4];
    const int* nn   = (const int*)d_in[5];
    float* out = (float*)d_out;

    ushort_t* X1t = (ushort_t*)d_ws;          // 64 MiB
    ushort_t* X2t = X1t + 33554432;           // +64 MiB

    lin_mfma_kernel<<<2048, 256, 0, stream>>>(X, W1, b1, W2, b2, nn, X1t, X2t);
    mmtr_kernel<<<2048, 256, 0, stream>>>(X1t, X2t, out, nn);
}